// Round 3
// baseline (958.315 us; speedup 1.0000x reference)
//
#include <hip/hip_runtime.h>

// SoftmaxPooling on MI355X (gfx950) — round 4: strip-streaming fused kernel.
//   scores = tanh(h @ W1 + b1) @ w2 (+b2, cancels in softmax)
//   per-track (10 consecutive hits) softmax -> weights
//   pooled[track] = sum_i w_i * h[i]
//
// History:
//   round 0 (340us/disp): full 135KiB LDS W1^T -> 1 block/CU, serialized phases, 24% occ.
//   round 1 (445us/disp): all-global B + launch_bounds(320,4) -> spill disaster.
//   round 2 (386us/disp): split-N W1 (64KB LDS + L2 half), occ 42%, BUT VGPR=64 again
//                         (compiler remat/spill around 64-reg live A-frags) and HBM stayed
//                         at 21%: per-block h load is ONE burst, then a long no-HBM MFMA
//                         phase -> bursty traffic, latency-bound regardless of occupancy.
// This round:
//   - wave processes 5 strips in a LOOP, one strip's A-frags live at a time (32 VGPR,
//     short live range) -> natural demand ~80 regs, fits 128 cap w/o spill
//   - h loads interleave with compute 5x per block -> HBM issue spread out
//   - per p-iteration: one LDS-fed + one L2-fed column-tile = 2 independent MFMA chains
//   - block = 64 tracks (640 rows, 40 strips), grid 782, 2 blocks/CU

typedef __attribute__((ext_vector_type(8))) short short8;  // 8 bf16 (4 VGPRs) MFMA A/B frag
typedef __attribute__((ext_vector_type(4))) float f32x4;   // MFMA C/D frag

#define LATENT       256
#define HPT          10                  // hits per track
#define TPB_TRACKS   64                  // tracks per block
#define ROWS_PB      (TPB_TRACKS * HPT)  // 640 hit-rows per block
#define STRIPS_PB    (ROWS_PB / 16)      // 40 MFMA row-strips per block
#define WAVES        8
#define THREADS      (WAVES * 64)        // 512
#define SPW          (STRIPS_PB / WAVES) // 5 strips per wave, uniform
#define LOG2E        1.44269504088896f

__device__ __forceinline__ short bf16_rne(float x) {
    // round-to-nearest-even fp32 -> bf16
    unsigned u = __float_as_uint(x);
    u += 0x7FFFu + ((u >> 16) & 1u);
    return (short)(u >> 16);
}

__device__ __forceinline__ float tanh_fast(float x) {
    // tanh(x) = 1 - 2/(e^{2x}+1); exp2-based, saturates correctly for |x| large
    float e = __builtin_amdgcn_exp2f(x * (2.0f * LOG2E));
    return 1.0f - 2.0f * __builtin_amdgcn_rcpf(e + 1.0f);
}

// ---------------- Pre-kernel: W1 fp32 [k][n] -> W1^T bf16 [n][k] linear in workspace ----------------
__global__ __launch_bounds__(256)
void convert_w1_kernel(const float* __restrict__ W1, short* __restrict__ w1t) {
    int idx = blockIdx.x * 256 + threadIdx.x;   // 0 .. 256*128-1
    int n = idx & 255;
    int k = (idx >> 8) << 1;
    short2 p;
    p.x = bf16_rne(W1[(size_t)k * LATENT + n]);
    p.y = bf16_rne(W1[(size_t)(k + 1) * LATENT + n]);
    *(short2*)&w1t[n * LATENT + k] = p;
}

__global__ __launch_bounds__(THREADS, 4)   // 4 waves/EU -> 2x 8-wave blocks/CU; VGPR cap 128
void softmax_pool_kernel(const float* __restrict__ h,
                         const short* __restrict__ w1t,   // bf16 W1^T [n][k] linear, L2-resident
                         const float* __restrict__ b1,
                         const float* __restrict__ w2,
                         float* __restrict__ out,
                         int n_hits, int num_tracks)
{
    __shared__ short w1_lds[128 * 256];      // lower-half W1^T bf16, XOR-swizzled, 65536 B
    __shared__ float sc_lds[ROWS_PB];        // scores then softmax weights, 2560 B

    const int tid  = threadIdx.x;
    const int wave = tid >> 6;
    const int lane = tid & 63;
    const int q    = lane >> 4;   // quad 0..3
    const int c    = lane & 15;   // low-4 lane id
    const int blk  = blockIdx.x;

    // ---------------- Phase A: stage lower W1^T half (n<128) into LDS, swizzled ----------------
    // 64 KiB = 4096 x 16B chunks; 8 iterations of 512 threads. Global reads linear/coalesced;
    // LDS writes at byte ^ ((n&7)<<4): residual 2-way conflict only (free). Verified round 2.
    {
        const char* src = (const char*)w1t;
        char* dst = (char*)w1_lds;
        #pragma unroll
        for (int it = 0; it < 8; ++it) {
            int chunk = it * THREADS + tid;
            int lin = chunk << 4;
            int sw  = lin ^ (((chunk >> 5) & 7) << 4);
            *(short8*)(dst + sw) = *(const short8*)(src + lin);
        }
    }
    __syncthreads();   // cheap (~64KB from L2); cross-block overlap hides it

    // ---------------- Phase B: strip loop — scores via MFMA ----------------
    // Wave w owns strips {w, w+8, w+16, w+24, w+32}; ONE strip's A-frags live at a time.
    #pragma unroll 1
    for (int s = 0; s < SPW; ++s) {
        const int strip = s * WAVES + wave;
        long row = (long)blk * ROWS_PB + strip * 16 + c;
        if (row >= n_hits) row = n_hits - 1;   // tail-block clamp (writes are guarded)
        const float* hrow = h + (size_t)row * LATENT + q * 8;

        // a[kt] = h[row][kt*32 + q*8 .. +7] as bf16  (32 VGPRs, strip-scoped)
        short8 a[8];
        #pragma unroll
        for (int kt = 0; kt < 8; ++kt) {
            float4 f0 = *(const float4*)(hrow + kt * 32);
            float4 f1 = *(const float4*)(hrow + kt * 32 + 4);
            short8 v;
            v[0] = bf16_rne(f0.x); v[1] = bf16_rne(f0.y);
            v[2] = bf16_rne(f0.z); v[3] = bf16_rne(f0.w);
            v[4] = bf16_rne(f1.x); v[5] = bf16_rne(f1.y);
            v[6] = bf16_rne(f1.z); v[7] = bf16_rne(f1.w);
            a[kt] = v;
        }

        f32x4 zero4 = {0.0f, 0.0f, 0.0f, 0.0f};
        f32x4 sc = zero4;   // score partials for rows strip*16 + q*4 .. +3

        // 8 p-iterations; each handles column-tile nA (LDS B) + nB = nA+128 (L2 B):
        // two independent MFMA chains, mixed LDS/VMEM pipes.
        #pragma unroll 1
        for (int p = 0; p < 8; ++p) {
            const int nA = p * 16 + c;
            const int nB = nA + 128;
            const char* lbase = (const char*)w1_lds;
            const int rowoff = nA * 512;
            const int swz = (nA & 7) << 4;
            const short* bbase = w1t + (size_t)nB * LATENT + q * 8;

            f32x4 accA = zero4, accB = zero4;
            #pragma unroll
            for (int kt = 0; kt < 8; ++kt) {
                short8 bfA = *(const short8*)(lbase + ((rowoff + kt * 64 + q * 16) ^ swz));
                short8 bfB = *(const short8*)(bbase + kt * 32);
                accA = __builtin_amdgcn_mfma_f32_16x16x32_bf16(a[kt], bfA, accA, 0, 0, 0);
                accB = __builtin_amdgcn_mfma_f32_16x16x32_bf16(a[kt], bfB, accB, 0, 0, 0);
            }
            // acc[r] = u[row = strip*16 + q*4 + r][n]; fold tanh + dot(w2)
            float b1A = b1[nA], w2A = w2[nA];
            float b1B = b1[nB], w2B = w2[nB];
            #pragma unroll
            for (int r = 0; r < 4; ++r)
                sc[r] += w2A * tanh_fast(accA[r] + b1A)
                       + w2B * tanh_fast(accB[r] + b1B);
        }

        // Reduce score partials across the 16 column-lanes (same quad)
        #pragma unroll
        for (int r = 0; r < 4; ++r) {
            float v = sc[r];
            v += __shfl_xor(v, 1);
            v += __shfl_xor(v, 2);
            v += __shfl_xor(v, 4);
            v += __shfl_xor(v, 8);
            sc[r] = v;
        }
        if (c == 0) {
            float4 o;
            o.x = sc[0]; o.y = sc[1]; o.z = sc[2]; o.w = sc[3];
            *(float4*)&sc_lds[strip * 16 + q * 4] = o;   // rows strip*16 + q*4 .. +3
        }
    }
    __syncthreads();

    // ---------------- Phase C: per-track softmax (scores -> weights, in place) ----------------
    if (tid < TPB_TRACKS) {
        int tg = blk * TPB_TRACKS + tid;
        if (tg < num_tracks) {
            float sv[HPT];
            float m = -1e30f;
            #pragma unroll
            for (int i = 0; i < HPT; ++i) {
                sv[i] = sc_lds[tid * HPT + i];
                m = fmaxf(m, sv[i]);
            }
            float sum = 0.0f;
            #pragma unroll
            for (int i = 0; i < HPT; ++i) {
                sv[i] = __builtin_amdgcn_exp2f((sv[i] - m) * LOG2E);
                sum += sv[i];
            }
            float inv = __builtin_amdgcn_rcpf(sum);
            #pragma unroll
            for (int i = 0; i < HPT; ++i)
                sc_lds[tid * HPT + i] = sv[i] * inv;
        }
    }
    __syncthreads();

    // ---------------- Phase D: weighted pooling ----------------
    // 8 tracks per wave; h slice L2-warm from Phase B. Lane owns 4 contiguous cols.
    #pragma unroll 1
    for (int i = 0; i < TPB_TRACKS / WAVES; ++i) {
        int t = wave * (TPB_TRACKS / WAVES) + i;
        int tg = blk * TPB_TRACKS + t;
        if (tg >= num_tracks) continue;
        const float* hb = h + (size_t)tg * HPT * LATENT + lane * 4;
        float4 acc = {0.0f, 0.0f, 0.0f, 0.0f};
        #pragma unroll
        for (int j = 0; j < HPT; ++j) {
            float wi = sc_lds[t * HPT + j];
            float4 v = *(const float4*)(hb + (size_t)j * LATENT);
            acc.x += wi * v.x;
            acc.y += wi * v.y;
            acc.z += wi * v.z;
            acc.w += wi * v.w;
        }
        *(float4*)(out + (size_t)tg * LATENT + lane * 4) = acc;
    }
}

extern "C" void kernel_launch(void* const* d_in, const int* in_sizes, int n_in,
                              void* d_out, int out_size, void* d_ws, size_t ws_size,
                              hipStream_t stream) {
    const float* h  = (const float*)d_in[0];
    const float* W1 = (const float*)d_in[1];
    const float* b1 = (const float*)d_in[2];
    const float* w2 = (const float*)d_in[3];
    // d_in[4] = b2 (cancels in softmax), d_in[5] = batch_indices (structure i/10 guaranteed)
    float* out = (float*)d_out;
    short* w1t = (short*)d_ws;               // 131072 B workspace: bf16 W1^T linear

    int n_hits     = in_sizes[0] / LATENT;    // 500000
    int num_tracks = out_size / LATENT;       // 50000
    int blocks     = (num_tracks + TPB_TRACKS - 1) / TPB_TRACKS;   // 782 (16-track tail)

    convert_w1_kernel<<<128, 256, 0, stream>>>(W1, w1t);
    softmax_pool_kernel<<<blocks, THREADS, 0, stream>>>(h, w1t, b1, w2, out,
                                                        n_hits, num_tracks);
}

// Round 4
// 737.193 us; speedup vs baseline: 1.3000x; 1.3000x over previous
//
#include <hip/hip_runtime.h>

// SoftmaxPooling on MI355X (gfx950) — round 5: A-in-LDS / B-in-registers inversion.
//   scores = tanh(h @ W1 + b1) @ w2 (+b2, cancels in softmax)
//   per-track (10 consecutive hits) softmax -> weights
//   pooled[track] = sum_i w_i * h[i]
//
// History:
//   round 0 (340us): W1^T fully in LDS (135KB) -> pure-LDS inner loop but 1 block/CU.
//   round 1 (445us): all-L2 B + bad launch_bounds -> spills.
//   round 2 (386us): split W1 LDS/L2 -> occ 42% but L2 B-loads inside inner loop.
//   round 3 (455us): strip-streaming -> per-strip exposed HBM burst + per-p exposed L2 latency.
//   Cross-round signal: every structure with global loads in the MFMA loop lost to round 0.
//   Pipe arithmetic: MFMA ~11us, VALU ~20us, HBM floor ~90us -> all rounds are latency-bound.
// This round:
//   - B (W1^T bf16) PINNED IN REGISTERS: wave w owns columns [32w,32w+32) = 2 chains
//     x 8 kt x short8 = 64 VGPR, loaded ONCE per block from the L2-resident workspace,
//     pinned with opaque asm (prevents the round-2/3 remat/sink pathology).
//   - A (h rows) staged ONCE per block into 80KB LDS tile, bf16, XOR-swizzled
//     (byte ^= (row&7)<<4 -> uniform bank use on ds_read_b128), coalesced 1KB-row bursts.
//   - inner loop per strip: 8 ds_read_b128 + 16 MFMA + tanh-fold. ZERO global access.
//   - cross-wave (column-split) score reduction aliased into the strip-0 LDS region,
//     which is dead after one barrier -> total LDS exactly 81920 B -> 2 blocks/CU.
//   - h converted fp32->bf16 once per element (staging), not once per wave per strip.
//   - block = 16 tracks (160 rows, 10 strips), grid = 3125 exact, no tail.

typedef __attribute__((ext_vector_type(8))) short short8;  // 8 bf16 (4 VGPRs) MFMA A/B frag
typedef __attribute__((ext_vector_type(4))) float f32x4;   // MFMA C/D frag

#define LATENT       256
#define HPT          10                  // hits per track
#define TPB_TRACKS   16                  // tracks per block
#define ROWS_PB      (TPB_TRACKS * HPT)  // 160 hit-rows per block
#define STRIPS_PB    (ROWS_PB / 16)      // 10 MFMA row-strips per block
#define WAVES        8
#define THREADS      (WAVES * 64)        // 512
#define LOG2E        1.44269504088896f

// smem layout (total 81920 B = exactly half of 160 KiB -> 2 blocks/CU):
//   [0, 81920)      h tile bf16: row r at r*512 + chunk16*16, byte ^ ((r&7)<<4)
//   after strip 0 is consumed (one barrier), its 8 KiB region is reused:
//   [0, 5120)       partial[wave][row] f32   (wave*640 + row*4)
//   [5120, 5760)    sc[row] f32 -> softmax weights in place

__device__ __forceinline__ short bf16_rne(float x) {
    // round-to-nearest-even fp32 -> bf16
    unsigned u = __float_as_uint(x);
    u += 0x7FFFu + ((u >> 16) & 1u);
    return (short)(u >> 16);
}

__device__ __forceinline__ float tanh_fast(float x) {
    // tanh(x) = 1 - 2/(e^{2x}+1); exp2-based, saturates correctly for |x| large
    float e = __builtin_amdgcn_exp2f(x * (2.0f * LOG2E));
    return 1.0f - 2.0f * __builtin_amdgcn_rcpf(e + 1.0f);
}

// ---------------- Pre-kernel: W1 fp32 [k][n] -> W1^T bf16 [n][k] linear in workspace ----------------
__global__ __launch_bounds__(256)
void convert_w1_kernel(const float* __restrict__ W1, short* __restrict__ w1t) {
    int idx = blockIdx.x * 256 + threadIdx.x;   // 0 .. 256*128-1
    int n = idx & 255;
    int k = (idx >> 8) << 1;
    short2 p;
    p.x = bf16_rne(W1[(size_t)k * LATENT + n]);
    p.y = bf16_rne(W1[(size_t)(k + 1) * LATENT + n]);
    *(short2*)&w1t[n * LATENT + k] = p;
}

// Per-strip score partial: wave computes its 2 column-chains over 16 rows from LDS A-frags.
// Returns (in lanes with c==0) the 4 row-partials for rows strip*16 + q*4 .. +3,
// summed over this wave's 32 columns.
__device__ __forceinline__ f32x4 strip_scores(const char* smem, int s, int c, int q,
                                              const short8* bA, const short8* bB,
                                              float b1A, float w2A, float b1B, float w2B)
{
    const int row = s * 16 + c;
    const char* abase = smem + row * 512;
    const int swz = (row & 7) << 4;
    f32x4 acc0 = {0.f, 0.f, 0.f, 0.f};
    f32x4 acc1 = {0.f, 0.f, 0.f, 0.f};
    #pragma unroll
    for (int kt = 0; kt < 8; ++kt) {
        // A-frag: h[row][kt*32 + q*8 .. +7]; one ds_read_b128 feeds BOTH chains
        short8 af = *(const short8*)(abase + ((q * 16 + kt * 64) ^ swz));
        acc0 = __builtin_amdgcn_mfma_f32_16x16x32_bf16(af, bA[kt], acc0, 0, 0, 0);
        acc1 = __builtin_amdgcn_mfma_f32_16x16x32_bf16(af, bB[kt], acc1, 0, 0, 0);
    }
    // acc*[r] = u[row = s*16 + q*4 + r][n]; fold tanh + dot(w2) for both column sets
    f32x4 part;
    #pragma unroll
    for (int r = 0; r < 4; ++r)
        part[r] = w2A * tanh_fast(acc0[r] + b1A) + w2B * tanh_fast(acc1[r] + b1B);
    // reduce across the 16 column-lanes (xor bits 0..3; q bits 4..5 untouched)
    #pragma unroll
    for (int r = 0; r < 4; ++r) {
        float v = part[r];
        v += __shfl_xor(v, 1);
        v += __shfl_xor(v, 2);
        v += __shfl_xor(v, 4);
        v += __shfl_xor(v, 8);
        part[r] = v;
    }
    return part;
}

__global__ __launch_bounds__(THREADS, 4)   // VGPR cap 128 -> 4 waves/EU = 2x 8-wave blocks/CU
void softmax_pool_kernel(const float* __restrict__ h,
                         const short* __restrict__ w1t,   // bf16 W1^T [n][k] linear, L2-resident
                         const float* __restrict__ b1,
                         const float* __restrict__ w2,
                         float* __restrict__ out,
                         int n_hits, int num_tracks)
{
    __shared__ __align__(16) char smem[81920];

    const int tid  = threadIdx.x;
    const int wave = tid >> 6;
    const int lane = tid & 63;
    const int q    = lane >> 4;   // quad 0..3
    const int c    = lane & 15;   // low-4 lane id
    const int blk  = blockIdx.x;

    // ---------------- Phase A: stage h tile -> LDS bf16, swizzled ----------------
    // Thread t covers row s*16 + (t>>5), cols (t&31)*8 .. +7 each pass: wave reads
    // 2 contiguous 1KB rows (perfectly coalesced); 8 f32 -> one swizzled ds_write_b128.
    {
        const int rsub = tid >> 5;          // 0..15
        const int c8   = tid & 31;          // 16B chunk within row
        const float* src0 = h + (size_t)(blk * ROWS_PB + rsub) * LATENT + c8 * 8;
        #pragma unroll 2
        for (int s = 0; s < STRIPS_PB; ++s) {
            const int row = s * 16 + rsub;
            const float* src = src0 + (size_t)s * 16 * LATENT;
            float4 f0 = *(const float4*)src;
            float4 f1 = *(const float4*)(src + 4);
            short8 v;
            v[0] = bf16_rne(f0.x); v[1] = bf16_rne(f0.y);
            v[2] = bf16_rne(f0.z); v[3] = bf16_rne(f0.w);
            v[4] = bf16_rne(f1.x); v[5] = bf16_rne(f1.y);
            v[6] = bf16_rne(f1.z); v[7] = bf16_rne(f1.w);
            int off = (row * 512 + c8 * 16) ^ ((row & 7) << 4);
            *(short8*)(smem + off) = v;
        }
    }

    // ---------------- Phase A2: pin this wave's B columns in registers ----------------
    // Wave w owns columns [32w, 32w+32): chain A = 32w + c, chain B = 32w + 16 + c.
    // 2 x 8 x short8 = 64 VGPR, loaded once from L2-resident w1t.
    const int nA = (wave << 5) + c;
    const int nB = nA + 16;
    short8 bA[8], bB[8];
    #pragma unroll
    for (int kt = 0; kt < 8; ++kt) {
        bA[kt] = *(const short8*)(w1t + (size_t)nA * LATENT + q * 8 + kt * 32);
        bB[kt] = *(const short8*)(w1t + (size_t)nB * LATENT + q * 8 + kt * 32);
    }
    // Opaque pin: make these asm-produced so the allocator cannot rematerialize them
    // by re-sinking the loads into the strip loop (the round-2/3 pathology).
    #pragma unroll
    for (int kt = 0; kt < 8; ++kt) {
        asm volatile("" : "+v"(bA[kt]));
        asm volatile("" : "+v"(bB[kt]));
    }
    const float b1A = b1[nA], w2A = w2[nA];
    const float b1B = b1[nB], w2B = w2[nB];

    __syncthreads();   // h tile visible

    // ---------------- Phase B: strip sweep, pure LDS + MFMA ----------------
    // Strip 0 first for ALL waves; after the barrier its 8KB region is dead and
    // becomes the score-partial scratch. Strips 1..9 then proceed barrier-free.
    f32x4 p0 = strip_scores(smem, 0, c, q, bA, bB, b1A, w2A, b1B, w2B);
    __syncthreads();   // every wave done READING strip-0 region
    if (c == 0)
        *(f32x4*)(smem + wave * 640 + q * 16) = p0;            // partial[wave][rows 0..15]

    #pragma unroll 1
    for (int s = 1; s < STRIPS_PB; ++s) {
        f32x4 p = strip_scores(smem, s, c, q, bA, bB, b1A, w2A, b1B, w2B);
        if (c == 0)
            *(f32x4*)(smem + wave * 640 + (s * 16 + q * 4) * 4) = p;
    }
    __syncthreads();   // all partials written

    // ---------------- Phase C1: cross-wave reduction ----------------
    if (tid < ROWS_PB) {
        float v = 0.f;
        #pragma unroll
        for (int w = 0; w < WAVES; ++w)
            v += *(const float*)(smem + w * 640 + tid * 4);
        *(float*)(smem + 5120 + tid * 4) = v;                  // sc[row]
    }
    __syncthreads();

    // ---------------- Phase C2: per-track softmax (scores -> weights, in place) ----------------
    if (tid < TPB_TRACKS) {
        float* scp = (float*)(smem + 5120) + tid * HPT;
        float sv[HPT];
        float m = -1e30f;
        #pragma unroll
        for (int i = 0; i < HPT; ++i) {
            sv[i] = scp[i];
            m = fmaxf(m, sv[i]);
        }
        float sum = 0.f;
        #pragma unroll
        for (int i = 0; i < HPT; ++i) {
            sv[i] = __builtin_amdgcn_exp2f((sv[i] - m) * LOG2E);
            sum += sv[i];
        }
        float inv = __builtin_amdgcn_rcpf(sum);
        #pragma unroll
        for (int i = 0; i < HPT; ++i)
            scp[i] = sv[i] * inv;
    }
    __syncthreads();

    // ---------------- Phase D: weighted pooling ----------------
    // 2 tracks per wave; h re-read f32 from global (L2/L3-warm — FETCH_SIZE across all
    // rounds confirms one HBM pass). Lane owns 4 contiguous cols. Weight read = LDS broadcast.
    const float* wts = (const float*)(smem + 5120);
    #pragma unroll
    for (int i = 0; i < 2; ++i) {
        int t = wave * 2 + i;
        int tg = blk * TPB_TRACKS + t;
        if (tg >= num_tracks) continue;
        const float* hb = h + (size_t)tg * HPT * LATENT + lane * 4;
        float4 acc = {0.f, 0.f, 0.f, 0.f};
        #pragma unroll
        for (int j = 0; j < HPT; ++j) {
            float wi = wts[t * HPT + j];
            float4 v = *(const float4*)(hb + (size_t)j * LATENT);
            acc.x += wi * v.x;
            acc.y += wi * v.y;
            acc.z += wi * v.z;
            acc.w += wi * v.w;
        }
        *(float4*)(out + (size_t)tg * LATENT + lane * 4) = acc;
    }
}

extern "C" void kernel_launch(void* const* d_in, const int* in_sizes, int n_in,
                              void* d_out, int out_size, void* d_ws, size_t ws_size,
                              hipStream_t stream) {
    const float* h  = (const float*)d_in[0];
    const float* W1 = (const float*)d_in[1];
    const float* b1 = (const float*)d_in[2];
    const float* w2 = (const float*)d_in[3];
    // d_in[4] = b2 (cancels in softmax), d_in[5] = batch_indices (structure i/10 guaranteed)
    float* out = (float*)d_out;
    short* w1t = (short*)d_ws;               // 131072 B workspace: bf16 W1^T linear

    int n_hits     = in_sizes[0] / LATENT;    // 500000
    int num_tracks = out_size / LATENT;       // 50000
    int blocks     = (num_tracks + TPB_TRACKS - 1) / TPB_TRACKS;   // 3125 exact, no tail

    convert_w1_kernel<<<128, 256, 0, stream>>>(W1, w1t);
    softmax_pool_kernel<<<blocks, THREADS, 0, stream>>>(h, w1t, b1, w2, out,
                                                        n_hits, num_tracks);
}

// Round 5
// 722.271 us; speedup vs baseline: 1.3268x; 1.0207x over previous
//
#include <hip/hip_runtime.h>

// SoftmaxPooling on MI355X (gfx950) — round 6: pipelined staging (T14 async-STAGE).
//   scores = tanh(h @ W1 + b1) @ w2 (+b2, cancels in softmax)
//   per-track (10 consecutive hits) softmax -> weights
//   pooled[track] = sum_i w_i * h[i]
//
// History:
//   round 0 (340us): W1^T fully in LDS -> pure-LDS loop but 1 block/CU.
//   rounds 1-3 (386-455us): global loads inside MFMA loop -> exposed latency, all regressions.
//   round 4 (~234us est): A-in-LDS / B-in-registers inversion, 80KB tile, 2 blocks/CU. WIN.
//     Remaining gap vs ~90us HBM floor: stage-all -> barrier -> compute serializes HBM
//     into a front burst (duty ~60%, effective 2.4 TB/s).
// This round (schedule-only change, structure identical to round 4):
//   - prologue stages strips 0-3 with batch-issued loads (8 float4 in flight/thread)
//   - 6 pipeline chunks: issue loads for strip 4+c -> compute strip c (loads fly under
//     MFMA/tanh; sched_barrier(0) pins issue order) -> convert+write strip 4+c -> barrier
//   - tail: strips 6-9 compute barrier-free
//   - partial-score region still aliases strip-0 LDS (dead after chunk-0 barrier);
//     staging writes (strips>=4, byte>=32768) never touch the partial region (<5760)
//   - LDS exactly 81920 B -> 2 blocks/CU; VGPR target <=128 under launch_bounds(512,4)

typedef __attribute__((ext_vector_type(8))) short short8;  // 8 bf16 (4 VGPRs) MFMA A/B frag
typedef __attribute__((ext_vector_type(4))) float f32x4;   // MFMA C/D frag

#define LATENT       256
#define HPT          10                  // hits per track
#define TPB_TRACKS   16                  // tracks per block
#define ROWS_PB      (TPB_TRACKS * HPT)  // 160 hit-rows per block
#define STRIPS_PB    (ROWS_PB / 16)      // 10 MFMA row-strips per block
#define WAVES        8
#define THREADS      (WAVES * 64)        // 512
#define PRO_STRIPS   4                   // strips staged in prologue
#define PIPE_CHUNKS  (STRIPS_PB - PRO_STRIPS)  // 6 pipelined stage chunks
#define LOG2E        1.44269504088896f

// smem layout (total 81920 B = exactly half of 160 KiB -> 2 blocks/CU):
//   [0, 81920)   h tile bf16: row r at r*512 + chunk16*16, byte ^ ((r&7)<<4)
//   after chunk-0 barrier strip 0's region [0,8192) is dead for reads; reused:
//   [0, 5120)    partial[wave][row] f32   (wave*640 + row*4)
//   [5120, 5760) sc[row] f32 -> softmax weights in place

__device__ __forceinline__ short bf16_rne(float x) {
    // round-to-nearest-even fp32 -> bf16
    unsigned u = __float_as_uint(x);
    u += 0x7FFFu + ((u >> 16) & 1u);
    return (short)(u >> 16);
}

__device__ __forceinline__ short8 pack_bf16x8(float4 f0, float4 f1) {
    short8 v;
    v[0] = bf16_rne(f0.x); v[1] = bf16_rne(f0.y);
    v[2] = bf16_rne(f0.z); v[3] = bf16_rne(f0.w);
    v[4] = bf16_rne(f1.x); v[5] = bf16_rne(f1.y);
    v[6] = bf16_rne(f1.z); v[7] = bf16_rne(f1.w);
    return v;
}

__device__ __forceinline__ float tanh_fast(float x) {
    // tanh(x) = 1 - 2/(e^{2x}+1); exp2-based, saturates correctly for |x| large
    float e = __builtin_amdgcn_exp2f(x * (2.0f * LOG2E));
    return 1.0f - 2.0f * __builtin_amdgcn_rcpf(e + 1.0f);
}

// ---------------- Pre-kernel: W1 fp32 [k][n] -> W1^T bf16 [n][k] linear in workspace ----------------
__global__ __launch_bounds__(256)
void convert_w1_kernel(const float* __restrict__ W1, short* __restrict__ w1t) {
    int idx = blockIdx.x * 256 + threadIdx.x;   // 0 .. 256*128-1
    int n = idx & 255;
    int k = (idx >> 8) << 1;
    short2 p;
    p.x = bf16_rne(W1[(size_t)k * LATENT + n]);
    p.y = bf16_rne(W1[(size_t)(k + 1) * LATENT + n]);
    *(short2*)&w1t[n * LATENT + k] = p;
}

// Per-strip score partial: wave computes its 2 column-chains over 16 rows from LDS A-frags.
// Returns the 4 row-partials for rows strip*16 + q*4 .. +3 (valid in lanes with c==0),
// summed over this wave's 32 columns.
__device__ __forceinline__ f32x4 strip_scores(const char* smem, int s, int c, int q,
                                              const short8* bA, const short8* bB,
                                              float b1A, float w2A, float b1B, float w2B)
{
    const int row = s * 16 + c;
    const char* abase = smem + row * 512;
    const int swz = (row & 7) << 4;
    f32x4 acc0 = {0.f, 0.f, 0.f, 0.f};
    f32x4 acc1 = {0.f, 0.f, 0.f, 0.f};
    #pragma unroll
    for (int kt = 0; kt < 8; ++kt) {
        // A-frag: h[row][kt*32 + q*8 .. +7]; one ds_read_b128 feeds BOTH chains
        short8 af = *(const short8*)(abase + ((q * 16 + kt * 64) ^ swz));
        acc0 = __builtin_amdgcn_mfma_f32_16x16x32_bf16(af, bA[kt], acc0, 0, 0, 0);
        acc1 = __builtin_amdgcn_mfma_f32_16x16x32_bf16(af, bB[kt], acc1, 0, 0, 0);
    }
    // acc*[r] = u[row = s*16 + q*4 + r][n]; fold tanh + dot(w2) for both column sets
    f32x4 part;
    #pragma unroll
    for (int r = 0; r < 4; ++r)
        part[r] = w2A * tanh_fast(acc0[r] + b1A) + w2B * tanh_fast(acc1[r] + b1B);
    // reduce across the 16 column-lanes (xor bits 0..3; q bits 4..5 untouched)
    #pragma unroll
    for (int r = 0; r < 4; ++r) {
        float v = part[r];
        v += __shfl_xor(v, 1);
        v += __shfl_xor(v, 2);
        v += __shfl_xor(v, 4);
        v += __shfl_xor(v, 8);
        part[r] = v;
    }
    return part;
}

__global__ __launch_bounds__(THREADS, 4)   // VGPR cap 128 -> 4 waves/EU = 2x 8-wave blocks/CU
void softmax_pool_kernel(const float* __restrict__ h,
                         const short* __restrict__ w1t,   // bf16 W1^T [n][k] linear, L2-resident
                         const float* __restrict__ b1,
                         const float* __restrict__ w2,
                         float* __restrict__ out,
                         int n_hits, int num_tracks)
{
    __shared__ __align__(16) char smem[81920];

    const int tid  = threadIdx.x;
    const int wave = tid >> 6;
    const int lane = tid & 63;
    const int q    = lane >> 4;   // quad 0..3
    const int c    = lane & 15;   // low-4 lane id
    const int blk  = blockIdx.x;

    // Staging coordinates: thread covers row (s*16 + rsub), 16B-chunk c8 of the bf16 row.
    const int rsub = tid >> 5;          // 0..15
    const int c8   = tid & 31;          // 16B chunk within 512B row

    // ---------------- Prologue: batch-issue loads for strips 0..3, then B-pins ----------------
    float4 pf[2 * PRO_STRIPS];
    {
        const float* src0 = h + ((size_t)blk * ROWS_PB + rsub) * LATENT + c8 * 8;
        #pragma unroll
        for (int s = 0; s < PRO_STRIPS; ++s) {
            const float* src = src0 + (size_t)s * 16 * LATENT;
            pf[2 * s]     = *(const float4*)src;
            pf[2 * s + 1] = *(const float4*)(src + 4);
        }
    }

    // Wave w owns columns [32w, 32w+32): chain A = 32w + c, chain B = 32w + 16 + c.
    // 2 x 8 x short8 = 64 VGPR, loaded once from L2-resident w1t (hides under HBM waits).
    const int nA = (wave << 5) + c;
    const int nB = nA + 16;
    short8 bA[8], bB[8];
    #pragma unroll
    for (int kt = 0; kt < 8; ++kt) {
        bA[kt] = *(const short8*)(w1t + (size_t)nA * LATENT + q * 8 + kt * 32);
        bB[kt] = *(const short8*)(w1t + (size_t)nB * LATENT + q * 8 + kt * 32);
    }
    // Opaque pin: prevent the allocator from re-sinking these loads into the strip loop
    // (the round-2/3 remat pathology).
    #pragma unroll
    for (int kt = 0; kt < 8; ++kt) {
        asm volatile("" : "+v"(bA[kt]));
        asm volatile("" : "+v"(bB[kt]));
    }
    const float b1A = b1[nA], w2A = w2[nA];
    const float b1B = b1[nB], w2B = w2[nB];

    // Convert + swizzled write of prologue strips
    #pragma unroll
    for (int s = 0; s < PRO_STRIPS; ++s) {
        const int row = s * 16 + rsub;
        short8 v = pack_bf16x8(pf[2 * s], pf[2 * s + 1]);
        int off = (row * 512 + c8 * 16) ^ ((row & 7) << 4);
        *(short8*)(smem + off) = v;
    }
    __syncthreads();   // strips 0..3 visible

    // ---------------- Pipelined Phase B: compute strip c while staging strip 4+c ----------------
    f32x4 pprev;
    #pragma unroll 1
    for (int cch = 0; cch < PIPE_CHUNKS; ++cch) {
        // issue next-strip loads (strip 4+cch) — in flight under the compute below
        const int srow = (PRO_STRIPS + cch) * 16 + rsub;
        const float* src = h + ((size_t)blk * ROWS_PB + srow) * LATENT + c8 * 8;
        float4 g0 = *(const float4*)src;
        float4 g1 = *(const float4*)(src + 4);
        __builtin_amdgcn_sched_barrier(0);   // pin: loads issue before compute, can't sink

        // compute current strip from LDS (pure DS+MFMA+VALU; vmcnt wait lands after)
        f32x4 p = strip_scores(smem, cch, c, q, bA, bB, b1A, w2A, b1B, w2B);

        // write PREVIOUS strip's partial (strip-0 region is dead after chunk-0 barrier)
        if (cch > 0 && c == 0)
            *(f32x4*)(smem + wave * 640 + ((cch - 1) * 16 + q * 4) * 4) = pprev;
        pprev = p;

        // convert + swizzled write of the staged strip
        short8 v = pack_bf16x8(g0, g1);
        int off = (srow * 512 + c8 * 16) ^ ((srow & 7) << 4);
        *(short8*)(smem + off) = v;

        __syncthreads();   // staged strip visible; chunk lockstep
    }

    // ---------------- Tail: strips 6..9, all staged, barrier-free ----------------
    #pragma unroll 1
    for (int s = PIPE_CHUNKS; s < STRIPS_PB; ++s) {
        f32x4 p = strip_scores(smem, s, c, q, bA, bB, b1A, w2A, b1B, w2B);
        if (c == 0)
            *(f32x4*)(smem + wave * 640 + ((s - 1) * 16 + q * 4) * 4) = pprev;
        pprev = p;
    }
    if (c == 0)
        *(f32x4*)(smem + wave * 640 + ((STRIPS_PB - 1) * 16 + q * 4) * 4) = pprev;
    __syncthreads();   // all partials written

    // ---------------- Phase C1: cross-wave reduction ----------------
    if (tid < ROWS_PB) {
        float v = 0.f;
        #pragma unroll
        for (int w = 0; w < WAVES; ++w)
            v += *(const float*)(smem + w * 640 + tid * 4);
        *(float*)(smem + 5120 + tid * 4) = v;                  // sc[row]
    }
    __syncthreads();

    // ---------------- Phase C2: per-track softmax (scores -> weights, in place) ----------------
    if (tid < TPB_TRACKS) {
        float* scp = (float*)(smem + 5120) + tid * HPT;
        float sv[HPT];
        float m = -1e30f;
        #pragma unroll
        for (int i = 0; i < HPT; ++i) {
            sv[i] = scp[i];
            m = fmaxf(m, sv[i]);
        }
        float sum = 0.f;
        #pragma unroll
        for (int i = 0; i < HPT; ++i) {
            sv[i] = __builtin_amdgcn_exp2f((sv[i] - m) * LOG2E);
            sum += sv[i];
        }
        float inv = __builtin_amdgcn_rcpf(sum);
        #pragma unroll
        for (int i = 0; i < HPT; ++i)
            scp[i] = sv[i] * inv;
    }
    __syncthreads();

    // ---------------- Phase D: weighted pooling ----------------
    // 2 tracks per wave; h re-read f32 from global (L2/L3-warm — FETCH_SIZE across rounds
    // confirms one HBM pass). Lane owns 4 contiguous cols. Weight read = LDS broadcast.
    const float* wts = (const float*)(smem + 5120);
    #pragma unroll
    for (int i = 0; i < 2; ++i) {
        int t = wave * 2 + i;
        int tg = blk * TPB_TRACKS + t;
        if (tg >= num_tracks) continue;
        const float* hb = h + (size_t)tg * HPT * LATENT + lane * 4;
        float4 acc = {0.f, 0.f, 0.f, 0.f};
        #pragma unroll
        for (int j = 0; j < HPT; ++j) {
            float wi = wts[t * HPT + j];
            float4 v = *(const float4*)(hb + (size_t)j * LATENT);
            acc.x += wi * v.x;
            acc.y += wi * v.y;
            acc.z += wi * v.z;
            acc.w += wi * v.w;
        }
        *(float4*)(out + (size_t)tg * LATENT + lane * 4) = acc;
    }
}

extern "C" void kernel_launch(void* const* d_in, const int* in_sizes, int n_in,
                              void* d_out, int out_size, void* d_ws, size_t ws_size,
                              hipStream_t stream) {
    const float* h  = (const float*)d_in[0];
    const float* W1 = (const float*)d_in[1];
    const float* b1 = (const float*)d_in[2];
    const float* w2 = (const float*)d_in[3];
    // d_in[4] = b2 (cancels in softmax), d_in[5] = batch_indices (structure i/10 guaranteed)
    float* out = (float*)d_out;
    short* w1t = (short*)d_ws;               // 131072 B workspace: bf16 W1^T linear

    int n_hits     = in_sizes[0] / LATENT;    // 500000
    int num_tracks = out_size / LATENT;       // 50000
    int blocks     = (num_tracks + TPB_TRACKS - 1) / TPB_TRACKS;   // 3125 exact, no tail

    convert_w1_kernel<<<128, 256, 0, stream>>>(W1, w1t);
    softmax_pool_kernel<<<blocks, THREADS, 0, stream>>>(h, w1t, b1, w2, out,
                                                        n_hits, num_tracks);
}

// Round 6
// 722.229 us; speedup vs baseline: 1.3269x; 1.0001x over previous
//
#include <hip/hip_runtime.h>

// SoftmaxPooling on MI355X (gfx950) — round 7: counted-vmcnt barriers + cheap reduction.
//   scores = tanh(h @ W1 + b1) @ w2 (+b2, cancels in softmax)
//   per-track (10 consecutive hits) softmax -> weights
//   pooled[track] = sum_i w_i * h[i]
//
// History:
//   round 0 (340us): W1^T fully in LDS -> 1 block/CU.
//   rounds 1-3 (386-455us): global loads in MFMA loop -> exposed latency, regressions.
//   round 4 (~234us): A-in-LDS / B-in-reg inversion, 80KB tile, 2 blocks/CU. WIN.
//   round 5 (~219us): depth-1 staged pipeline. Small win only — __syncthreads drains
//     vmcnt(0) (m97), so in-flight loads were force-completed at every chunk barrier;
//     and the 16-shfl/strip reduction loads the same LDS pipe as A-frag ds_reads.
// This round (schedule-only; geometry/layout identical to round 5):
//   - in-loop barriers = lgkmcnt(0)-only drain + raw s_barrier (+sched_barrier fences):
//     ds_write visibility kept, global loads stay in flight ACROSS barriers (T4)
//   - staging depth 2: strips 4..9 via two rotating 2xfloat4 slots, issued one chunk
//     ahead of consumption -> ~1300cy cover vs ~900cy HBM latency
//   - score reduction: 5-shfl multi-value butterfly (lane c owns row q*4+(c&3))
//     instead of 16 shfl -> 69% less bpermute traffic on the LDS pipe
//   - LDS exactly 81920 B -> 2 blocks/CU; VGPR ~107 under launch_bounds(512,4)

typedef __attribute__((ext_vector_type(8))) short short8;  // 8 bf16 (4 VGPRs) MFMA A/B frag
typedef __attribute__((ext_vector_type(4))) float f32x4;   // MFMA C/D frag

#define LATENT       256
#define HPT          10                  // hits per track
#define TPB_TRACKS   16                  // tracks per block
#define ROWS_PB      (TPB_TRACKS * HPT)  // 160 hit-rows per block
#define STRIPS_PB    (ROWS_PB / 16)      // 10 MFMA row-strips per block
#define WAVES        8
#define THREADS      (WAVES * 64)        // 512
#define PRO_STRIPS   4                   // strips staged in prologue
#define PIPE_CHUNKS  (STRIPS_PB - PRO_STRIPS)  // 6 pipelined stage chunks
#define LOG2E        1.44269504088896f

// smem layout (total 81920 B = exactly half of 160 KiB -> 2 blocks/CU):
//   [0, 81920)   h tile bf16: row r at r*512 + chunk16*16, byte ^ ((r&7)<<4)
//   after chunk-0 barrier strip 0's region [0,8192) is dead for reads; reused:
//   [0, 5120)    partial[wave][row] f32   (wave*640 + row*4)
//   [5120, 5760) sc[row] f32 -> softmax weights in place

__device__ __forceinline__ short bf16_rne(float x) {
    // round-to-nearest-even fp32 -> bf16
    unsigned u = __float_as_uint(x);
    u += 0x7FFFu + ((u >> 16) & 1u);
    return (short)(u >> 16);
}

__device__ __forceinline__ short8 pack_bf16x8(float4 f0, float4 f1) {
    short8 v;
    v[0] = bf16_rne(f0.x); v[1] = bf16_rne(f0.y);
    v[2] = bf16_rne(f0.z); v[3] = bf16_rne(f0.w);
    v[4] = bf16_rne(f1.x); v[5] = bf16_rne(f1.y);
    v[6] = bf16_rne(f1.z); v[7] = bf16_rne(f1.w);
    return v;
}

__device__ __forceinline__ float tanh_fast(float x) {
    // tanh(x) = 1 - 2/(e^{2x}+1); exp2-based, saturates correctly for |x| large
    float e = __builtin_amdgcn_exp2f(x * (2.0f * LOG2E));
    return 1.0f - 2.0f * __builtin_amdgcn_rcpf(e + 1.0f);
}

// LDS-only barrier: drains ds ops (visibility of staged strip + partials) but leaves
// global loads in flight (T4 counted-vmcnt pattern; __syncthreads would drain vmcnt(0)).
// sched_barrier(0) fences per rule #18 (hipcc hoists ops past inline-asm waitcnt).
__device__ __forceinline__ void barrier_lds_only() {
    __builtin_amdgcn_sched_barrier(0);
    asm volatile("s_waitcnt lgkmcnt(0)" ::: "memory");
    __builtin_amdgcn_s_barrier();
    __builtin_amdgcn_sched_barrier(0);
}

// ---------------- Pre-kernel: W1 fp32 [k][n] -> W1^T bf16 [n][k] linear in workspace ----------------
__global__ __launch_bounds__(256)
void convert_w1_kernel(const float* __restrict__ W1, short* __restrict__ w1t) {
    int idx = blockIdx.x * 256 + threadIdx.x;   // 0 .. 256*128-1
    int n = idx & 255;
    int k = (idx >> 8) << 1;
    short2 p;
    p.x = bf16_rne(W1[(size_t)k * LATENT + n]);
    p.y = bf16_rne(W1[(size_t)(k + 1) * LATENT + n]);
    *(short2*)&w1t[n * LATENT + k] = p;
}

// Per-strip score: wave computes its 2 column-chains over 16 rows from LDS A-frags,
// folds tanh+w2, then reduces across the 16 column-lanes with a 5-shfl multi-value
// butterfly. Returns the full row sum; lane c owns row q*4 + (c&3) (4 copies over c>>2).
__device__ __forceinline__ float strip_scores(const char* smem, int s, int c, int q,
                                              const short8* bA, const short8* bB,
                                              float b1A, float w2A, float b1B, float w2B)
{
    const int row = s * 16 + c;
    const char* abase = smem + row * 512;
    const int swz = (row & 7) << 4;
    f32x4 acc0 = {0.f, 0.f, 0.f, 0.f};
    f32x4 acc1 = {0.f, 0.f, 0.f, 0.f};
    #pragma unroll
    for (int kt = 0; kt < 8; ++kt) {
        // A-frag: h[row][kt*32 + q*8 .. +7]; one ds_read_b128 feeds BOTH chains
        short8 af = *(const short8*)(abase + ((q * 16 + kt * 64) ^ swz));
        acc0 = __builtin_amdgcn_mfma_f32_16x16x32_bf16(af, bA[kt], acc0, 0, 0, 0);
        acc1 = __builtin_amdgcn_mfma_f32_16x16x32_bf16(af, bB[kt], acc1, 0, 0, 0);
    }
    float part[4];
    #pragma unroll
    for (int r = 0; r < 4; ++r)
        part[r] = w2A * tanh_fast(acc0[r] + b1A) + w2B * tanh_fast(acc1[r] + b1B);

    // Multi-value butterfly: 5 shfls (was 16). Step 1 (xor 1): pair (p0,p1),(p2,p3);
    // each lane keeps the row matching its bit0 and receives the partner's copy.
    float s01 = (c & 1) ? part[0] : part[1];            // send the row we don't keep
    float r01 = __shfl_xor(s01, 1);
    float a0  = ((c & 1) ? part[1] : part[0]) + r01;    // row (c&1), 2-lane sum
    float s23 = (c & 1) ? part[2] : part[3];
    float r23 = __shfl_xor(s23, 1);
    float a1  = ((c & 1) ? part[3] : part[2]) + r23;    // row 2+(c&1), 2-lane sum
    // Step 2 (xor 2): pair (a0,a1); lane keeps row c&3, 4-lane sum.
    float sp = (c & 2) ? a0 : a1;
    float rp = __shfl_xor(sp, 2);
    float b  = ((c & 2) ? a1 : a0) + rp;
    // Steps 3,4: plain butterfly over bits 2,3 -> full 16-lane sum.
    b += __shfl_xor(b, 4);
    b += __shfl_xor(b, 8);
    return b;   // row q*4 + (c&3)
}

__global__ __launch_bounds__(THREADS, 4)   // VGPR cap 128 -> 4 waves/EU = 2x 8-wave blocks/CU
void softmax_pool_kernel(const float* __restrict__ h,
                         const short* __restrict__ w1t,   // bf16 W1^T [n][k] linear, L2-resident
                         const float* __restrict__ b1,
                         const float* __restrict__ w2,
                         float* __restrict__ out,
                         int n_hits, int num_tracks)
{
    __shared__ __align__(16) char smem[81920];

    const int tid  = threadIdx.x;
    const int wave = tid >> 6;
    const int lane = tid & 63;
    const int q    = lane >> 4;   // quad 0..3
    const int c    = lane & 15;   // low-4 lane id
    const int blk  = blockIdx.x;

    // Staging coordinates: thread covers row (s*16 + rsub), 16B-chunk c8 of the bf16 row.
    const int rsub = tid >> 5;          // 0..15
    const int c8   = tid & 31;          // 16B chunk within 512B row
    const float* hbase = h + ((size_t)blk * ROWS_PB + rsub) * LATENT + c8 * 8;

    // ---------------- Prologue: batch-issue loads for strips 0..3, then B-pins ----------------
    float4 pf[2 * PRO_STRIPS];
    #pragma unroll
    for (int s = 0; s < PRO_STRIPS; ++s) {
        const float* src = hbase + (size_t)s * 16 * LATENT;
        pf[2 * s]     = *(const float4*)src;
        pf[2 * s + 1] = *(const float4*)(src + 4);
    }

    // Wave w owns columns [32w, 32w+32): chain A = 32w + c, chain B = 32w + 16 + c.
    // 2 x 8 x short8 = 64 VGPR, loaded once from L2-resident w1t (hides under HBM waits).
    const int nA = (wave << 5) + c;
    const int nB = nA + 16;
    short8 bA[8], bB[8];
    #pragma unroll
    for (int kt = 0; kt < 8; ++kt) {
        bA[kt] = *(const short8*)(w1t + (size_t)nA * LATENT + q * 8 + kt * 32);
        bB[kt] = *(const short8*)(w1t + (size_t)nB * LATENT + q * 8 + kt * 32);
    }
    // Opaque pin: prevent the allocator from re-sinking these loads into the strip loop
    // (the round-2/3 remat pathology).
    #pragma unroll
    for (int kt = 0; kt < 8; ++kt) {
        asm volatile("" : "+v"(bA[kt]));
        asm volatile("" : "+v"(bB[kt]));
    }
    const float b1A = b1[nA], w2A = w2[nA];
    const float b1B = b1[nB], w2B = w2[nB];

    // Convert + swizzled write of prologue strips (pf dies here, freeing 32 VGPR)
    #pragma unroll
    for (int s = 0; s < PRO_STRIPS; ++s) {
        const int row = s * 16 + rsub;
        int off = (row * 512 + c8 * 16) ^ ((row & 7) << 4);
        *(short8*)(smem + off) = pack_bf16x8(pf[2 * s], pf[2 * s + 1]);
    }

    // Issue in-flight loads for strips 4 and 5 (two slots); they cross the barrier
    // un-drained and get consumed at chunks 0 and 1.
    float4 gA0, gA1, gB0, gB1;
    {
        const float* s4 = hbase + (size_t)4 * 16 * LATENT;
        gA0 = *(const float4*)s4;  gA1 = *(const float4*)(s4 + 4);
        const float* s5 = hbase + (size_t)5 * 16 * LATENT;
        gB0 = *(const float4*)s5;  gB1 = *(const float4*)(s5 + 4);
    }
    barrier_lds_only();   // strips 0..3 visible; strip-4/5 loads remain in flight

    // ---------------- Pipelined Phase B: compute strip cch while staging strip 4+cch ----------------
    float pprev = 0.f;
    #pragma unroll 2      // folds the slot parity (cch&1) at compile time
    for (int cch = 0; cch < PIPE_CHUNKS; ++cch) {
        float p = strip_scores(smem, cch, c, q, bA, bB, b1A, w2A, b1B, w2B);

        // write PREVIOUS strip's partial (strip-0 region is dead after chunk-0 barrier)
        if (cch > 0 && c < 4)
            *(float*)(smem + wave * 640 + ((cch - 1) * 16 + q * 4 + c) * 4) = pprev;
        pprev = p;

        // consume slot (cch&1) = strip 4+cch: counted vmcnt wait (never 0), convert, write
        const int srow = (PRO_STRIPS + cch) * 16 + rsub;
        const int soff = (srow * 512 + c8 * 16) ^ ((srow & 7) << 4);
        if ((cch & 1) == 0) {
            *(short8*)(smem + soff) = pack_bf16x8(gA0, gA1);
            if (cch < PIPE_CHUNKS - 2) {    // refill slot A with strip 6+cch
                const float* sn = hbase + (size_t)(6 + cch) * 16 * LATENT;
                gA0 = *(const float4*)sn;  gA1 = *(const float4*)(sn + 4);
            }
        } else {
            *(short8*)(smem + soff) = pack_bf16x8(gB0, gB1);
            if (cch < PIPE_CHUNKS - 2) {    // refill slot B with strip 6+cch
                const float* sn = hbase + (size_t)(6 + cch) * 16 * LATENT;
                gB0 = *(const float4*)sn;  gB1 = *(const float4*)(sn + 4);
            }
        }
        barrier_lds_only();   // staged strip visible; refill loads stay in flight
    }

    // ---------------- Tail: strips 6..9, all staged, barrier-free ----------------
    #pragma unroll 1
    for (int s = PIPE_CHUNKS; s < STRIPS_PB; ++s) {
        float p = strip_scores(smem, s, c, q, bA, bB, b1A, w2A, b1B, w2B);
        if (c < 4)
            *(float*)(smem + wave * 640 + ((s - 1) * 16 + q * 4 + c) * 4) = pprev;
        pprev = p;
    }
    if (c < 4)
        *(float*)(smem + wave * 640 + ((STRIPS_PB - 1) * 16 + q * 4 + c) * 4) = pprev;
    __syncthreads();   // all partials written (full barrier fine: no loads in flight)

    // ---------------- Phase C1: cross-wave reduction ----------------
    if (tid < ROWS_PB) {
        float v = 0.f;
        #pragma unroll
        for (int w = 0; w < WAVES; ++w)
            v += *(const float*)(smem + w * 640 + tid * 4);
        *(float*)(smem + 5120 + tid * 4) = v;                  // sc[row]
    }
    __syncthreads();

    // ---------------- Phase C2: per-track softmax (scores -> weights, in place) ----------------
    if (tid < TPB_TRACKS) {
        float* scp = (float*)(smem + 5120) + tid * HPT;
        float sv[HPT];
        float m = -1e30f;
        #pragma unroll
        for (int i = 0; i < HPT; ++i) {
            sv[i] = scp[i];
            m = fmaxf(m, sv[i]);
        }
        float sum = 0.f;
        #pragma unroll
        for (int i = 0; i < HPT; ++i) {
            sv[i] = __builtin_amdgcn_exp2f((sv[i] - m) * LOG2E);
            sum += sv[i];
        }
        float inv = __builtin_amdgcn_rcpf(sum);
        #pragma unroll
        for (int i = 0; i < HPT; ++i)
            scp[i] = sv[i] * inv;
    }
    __syncthreads();

    // ---------------- Phase D: weighted pooling ----------------
    // 2 tracks per wave; h re-read f32 from global (L2/L3-warm — FETCH_SIZE across rounds
    // confirms one HBM pass). Lane owns 4 contiguous cols. Weight read = LDS broadcast.
    const float* wts = (const float*)(smem + 5120);
    #pragma unroll
    for (int i = 0; i < 2; ++i) {
        int t = wave * 2 + i;
        int tg = blk * TPB_TRACKS + t;
        if (tg >= num_tracks) continue;
        const float* hb = h + (size_t)tg * HPT * LATENT + lane * 4;
        float4 acc = {0.f, 0.f, 0.f, 0.f};
        #pragma unroll
        for (int j = 0; j < HPT; ++j) {
            float wi = wts[t * HPT + j];
            float4 v = *(const float4*)(hb + (size_t)j * LATENT);
            acc.x += wi * v.x;
            acc.y += wi * v.y;
            acc.z += wi * v.z;
            acc.w += wi * v.w;
        }
        *(float4*)(out + (size_t)tg * LATENT + lane * 4) = acc;
    }
}

extern "C" void kernel_launch(void* const* d_in, const int* in_sizes, int n_in,
                              void* d_out, int out_size, void* d_ws, size_t ws_size,
                              hipStream_t stream) {
    const float* h  = (const float*)d_in[0];
    const float* W1 = (const float*)d_in[1];
    const float* b1 = (const float*)d_in[2];
    const float* w2 = (const float*)d_in[3];
    // d_in[4] = b2 (cancels in softmax), d_in[5] = batch_indices (structure i/10 guaranteed)
    float* out = (float*)d_out;
    short* w1t = (short*)d_ws;               // 131072 B workspace: bf16 W1^T linear

    int n_hits     = in_sizes[0] / LATENT;    // 500000
    int num_tracks = out_size / LATENT;       // 50000
    int blocks     = (num_tracks + TPB_TRACKS - 1) / TPB_TRACKS;   // 3125 exact, no tail

    convert_w1_kernel<<<128, 256, 0, stream>>>(W1, w1t);
    softmax_pool_kernel<<<blocks, THREADS, 0, stream>>>(h, w1t, b1, w2, out,
                                                        n_hits, num_tracks);
}